// Round 1
// baseline (2626.693 us; speedup 1.0000x reference)
//
#include <hip/hip_runtime.h>
#include <hip/hip_bf16.h>

#define D 128
#define NK 16
#define BT (64*2048)

// ---------------- Setup: per-state Cholesky -> Linv -> P = Linv^T Linv ----------------
// one block per k, 128 threads
__global__ __launch_bounds__(128) void setup_kernel(const float* __restrict__ sigma,
                                                    float* __restrict__ Pout,
                                                    float* __restrict__ logdet) {
  __shared__ float A[D][129];   // sigma -> L (lower)
  __shared__ float V[D][129];   // Linv (lower), upper zeroed
  const int tid = threadIdx.x;
  const int k = blockIdx.x;
  const float* S = sigma + (size_t)k * D * D;

  for (int t = tid; t < D * D; t += 128) {
    A[t >> 7][t & 127] = S[t];
    V[t >> 7][t & 127] = 0.f;
  }
  __syncthreads();

  // Cholesky (right-looking), row per thread
  for (int j = 0; j < D; ++j) {
    if (tid == j) A[j][j] = sqrtf(A[j][j]);
    __syncthreads();
    const float inv = 1.f / A[j][j];
    if (tid > j) A[tid][j] *= inv;
    __syncthreads();
    if (tid > j) {
      const float lij = A[tid][j];
      for (int l = j + 1; l <= tid; ++l) A[tid][l] -= lij * A[l][j];
    }
    __syncthreads();
  }

  if (tid == 0) {
    float s = 0.f;
    for (int j = 0; j < D; ++j) s += logf(A[j][j]);
    logdet[k] = s;
  }

  // Linv: thread = column c, forward substitution (own column only -> no races)
  {
    const int c = tid;
    V[c][c] = 1.f / A[c][c];
    for (int r = c + 1; r < D; ++r) {
      float s = 0.f;
      for (int p = c; p < r; ++p) s += A[r][p] * V[p][c];
      V[r][c] = -s / A[r][r];
    }
  }
  __syncthreads();

  // P[i][j] = sum_r V[r][i] * V[r][j]; thread = column j (coalesced store)
  for (int i = 0; i < D; ++i) {
    float s = 0.f;
    for (int r = i; r < D; ++r) s += V[r][i] * V[r][tid];  // V upper = 0 handles r<tid
    Pout[((size_t)k * D + i) * D + tid] = s;
  }
}

__global__ void zero_kernel(float* o) { o[0] = 0.f; }

// ---------------- Main: maha = d^T P d, weighted by probs, global reduce ----------------
// block = 256 threads = 256 points; grid = BT/256 = 512
__global__ __launch_bounds__(256, 1) void main_kernel(const float* __restrict__ x,
                                                      const float* __restrict__ probs,
                                                      const float* __restrict__ mu,
                                                      const float* __restrict__ P,
                                                      const float* __restrict__ logdet,
                                                      float* __restrict__ out) {
  __shared__ float xl[256][129];    // 132 KB, stride 129 -> 2-way bank aliasing (free)
  __shared__ float PT[D][32];       // PT[j][r] = P[k][i0+r][j], rows 128B-aligned
  __shared__ float mul[NK * D];
  __shared__ float ldl[NK];
  __shared__ float red[256];

  const int tid = threadIdx.x;
  const size_t p0 = (size_t)blockIdx.x * 256;

  // stage x tile: 256 threads * float4 = 4KB = 8 rows per pass
  for (int pass = 0; pass < 32; ++pass) {
    const int u = pass * 8 + (tid >> 5);
    const int j = (tid & 31) * 4;
    const float4 v = *reinterpret_cast<const float4*>(&x[(p0 + u) * D + j]);
    xl[u][j + 0] = v.x; xl[u][j + 1] = v.y; xl[u][j + 2] = v.z; xl[u][j + 3] = v.w;
  }
  for (int t = tid; t < NK * D; t += 256) mul[t] = mu[t];
  if (tid < NK) ldl[tid] = logdet[tid];

  float vpt = 0.f;  // sum_k p_k*(0.5*maha_k + logdet_k)

  for (int k = 0; k < NK; ++k) {
    const float* mk = &mul[k * D];
    float maha = 0.f;
    for (int i0 = 0; i0 < D; i0 += 32) {
      __syncthreads();  // previous chunk fully consumed (also covers x staging)
      // stage PT (transposed chunk): 4096 floats, coalesced global reads
      for (int t = tid; t < 32 * D; t += 256) {
        const int r = t >> 7, j = t & 127;
        PT[j][r] = P[((size_t)(k * D + i0 + r)) * D + j];
      }
      __syncthreads();

      float y[32];
#pragma unroll
      for (int r = 0; r < 32; ++r) y[r] = 0.f;

      for (int j = 0; j < D; ++j) {
        const float dj = xl[tid][j] - mk[j];
#pragma unroll
        for (int rq = 0; rq < 8; ++rq) {
          const float4 q = *reinterpret_cast<const float4*>(&PT[j][rq * 4]);  // broadcast
          y[rq * 4 + 0] += q.x * dj;
          y[rq * 4 + 1] += q.y * dj;
          y[rq * 4 + 2] += q.z * dj;
          y[rq * 4 + 3] += q.w * dj;
        }
      }
#pragma unroll
      for (int r = 0; r < 32; ++r) maha += (xl[tid][i0 + r] - mk[i0 + r]) * y[r];
    }
    const float p = probs[(p0 + tid) * NK + k];
    vpt += p * (0.5f * maha + ldl[k]);
  }
  vpt += 117.62413225f;  // 0.5*D*ln(2*pi), uses sum_k p_k == 1

  __syncthreads();
  red[tid] = vpt;
  __syncthreads();
  for (int s = 128; s > 0; s >>= 1) {
    if (tid < s) red[tid] += red[tid + s];
    __syncthreads();
  }
  if (tid == 0) atomicAdd(out, red[0] * (1.0f / 64.0f));
}

extern "C" void kernel_launch(void* const* d_in, const int* in_sizes, int n_in,
                              void* d_out, int out_size, void* d_ws, size_t ws_size,
                              hipStream_t stream) {
  const float* x     = (const float*)d_in[0];
  const float* mu    = (const float*)d_in[1];
  const float* sigma = (const float*)d_in[2];
  const float* probs = (const float*)d_in[3];
  float* out = (float*)d_out;

  float* P      = (float*)d_ws;                  // 16*128*128 f32 = 1 MB
  float* logdet = P + (size_t)NK * D * D;        // +16 f32

  setup_kernel<<<NK, 128, 0, stream>>>(sigma, P, logdet);
  zero_kernel<<<1, 1, 0, stream>>>(out);
  main_kernel<<<BT / 256, 256, 0, stream>>>(x, probs, mu, P, logdet, out);
}

// Round 2
// 448.787 us; speedup vs baseline: 5.8529x; 5.8529x over previous
//
#include <hip/hip_runtime.h>
#include <hip/hip_bf16.h>

#define D 128
#define NK 16
#define BT (64*2048)

typedef short bf16x8 __attribute__((ext_vector_type(8)));
typedef float f32x4 __attribute__((ext_vector_type(4)));

__device__ __forceinline__ unsigned short f2bf(float f) {
  unsigned u = __builtin_bit_cast(unsigned, f);
  unsigned r = (u + 0x7FFFu + ((u >> 16) & 1u)) >> 16;   // round-to-nearest-even
  return (unsigned short)r;
}
__device__ __forceinline__ float bf2f(unsigned short h) {
  unsigned u = ((unsigned)h) << 16;
  return __builtin_bit_cast(float, u);
}

// ---------------- Setup: Cholesky -> logdet, Linv (bf16 swizzled image), Lmu = Linv*mu ----------
__global__ __launch_bounds__(128) void setup_kernel(const float* __restrict__ sigma,
                                                    const float* __restrict__ mu,
                                                    unsigned short* __restrict__ WG,
                                                    float* __restrict__ LmuG,
                                                    float* __restrict__ ldG) {
  __shared__ float A[D][129];
  __shared__ float V[D][129];
  const int tid = threadIdx.x;
  const int k = blockIdx.x;
  const float* S = sigma + (size_t)k * D * D;

  for (int t = tid; t < D * D; t += 128) {
    A[t >> 7][t & 127] = S[t];
    V[t >> 7][t & 127] = 0.f;
  }
  __syncthreads();

  // Cholesky (right-looking), row per thread
  for (int j = 0; j < D; ++j) {
    if (tid == j) A[j][j] = sqrtf(A[j][j]);
    __syncthreads();
    const float inv = 1.f / A[j][j];
    if (tid > j) A[tid][j] *= inv;
    __syncthreads();
    if (tid > j) {
      const float lij = A[tid][j];
      for (int l = j + 1; l <= tid; ++l) A[tid][l] -= lij * A[l][j];
    }
    __syncthreads();
  }

  if (tid == 0) {
    float s = 0.f;
    for (int j = 0; j < D; ++j) s += logf(A[j][j]);
    ldG[k] = s;
  }

  // Linv: thread = column c (independent, no races; V upper stays 0)
  {
    const int c = tid;
    V[c][c] = 1.f / A[c][c];
    for (int r = c + 1; r < D; ++r) {
      float s = 0.f;
      for (int p = c; p < r; ++p) s += A[r][p] * V[p][c];
      V[r][c] = -s / A[r][r];
    }
  }
  __syncthreads();

  // Lmu[k][j] = sum_i Linv[j][i] * mu[k][i]   (fp32, thread = row j)
  {
    const float* muk = mu + k * D;
    float s = 0.f;
    for (int i = 0; i <= tid; ++i) s += V[tid][i] * muk[i];
    LmuG[k * D + tid] = s;
  }

  // bf16 image of Linv, pre-swizzled so linear global_load_lds lands XOR-swizzled in LDS
  for (int t = tid; t < D * D; t += 128) {
    const int j = t >> 7, i = t & 127;
    WG[(size_t)k * D * D + j * D + (i ^ ((j & 7) << 3))] = f2bf(V[j][i]);
  }
}

__global__ void zero_kernel(float* o) { o[0] = 0.f; }

__device__ __forceinline__ void stage_tile(const unsigned short* gsrc, unsigned short* lds, int tid) {
#pragma unroll
  for (int c = 0; c < 4; ++c) {
    const int off = c * 4096 + tid * 8;  // u16 units; 16B per lane
    __builtin_amdgcn_global_load_lds(
        (const __attribute__((address_space(1))) unsigned int*)(gsrc + off),
        (__attribute__((address_space(3))) unsigned int*)(lds + off), 16, 0, 0);
  }
}

// ---------------- Main: Z^T = Linv * x^T per state (MFMA), maha = ||Z - Lmu||^2 ----------------
// 512 threads = 8 waves (2 j-groups x 4 bt-groups), 256 points/block, grid = 512
__global__ __launch_bounds__(512, 2) void main_kernel(const float* __restrict__ x,
                                                      const float* __restrict__ probs,
                                                      const unsigned short* __restrict__ WG,
                                                      const float* __restrict__ LmuG,
                                                      const float* __restrict__ ldG,
                                                      float* __restrict__ out) {
  __shared__ unsigned short xbuf[256 * 128];        // 64 KB, XOR-swizzled bf16 x
  __shared__ unsigned short Albuf[2][128 * 128];    // 64 KB, double-buffered swizzled Linv
  __shared__ float Lm[NK * D];                      // 8 KB
  __shared__ unsigned short pT[256 * 17];           // 8.5 KB, bf16 probs (padded stride 17)
  __shared__ float mah2[2][2][256];                 // 8 KB
  __shared__ float ld_s[NK];
  __shared__ float red[256];

  const int tid = threadIdx.x;
  const int ln = tid & 63;
  const int wid = tid >> 6;
  const int jg = wid >> 2;        // 0..1 : which 64 of the 128 z-dims
  const int bg = wid & 3;         // 0..3 : which 64 of the 256 points
  const int l15 = ln & 15, lg = ln >> 4;
  const size_t p0 = (size_t)blockIdx.x * 256;

  // stage x tile: fp32 -> bf16, XOR-swizzled writes (coalesced float4 reads)
  for (int t = tid; t < 256 * 128 / 4; t += 512) {
    const float4 v = *reinterpret_cast<const float4*>(&x[p0 * D + (size_t)t * 4]);
    const int flat = t * 4, row = flat >> 7, col = flat & 127;
    ushort4 h;
    h.x = f2bf(v.x); h.y = f2bf(v.y); h.z = f2bf(v.z); h.w = f2bf(v.w);
    *reinterpret_cast<ushort4*>(&xbuf[row * 128 + (col ^ ((row & 7) << 3))]) = h;
  }
  for (int t = tid; t < 256 * 16; t += 512)
    pT[(t >> 4) * 17 + (t & 15)] = f2bf(probs[p0 * NK + t]);
  for (int t = tid; t < NK * D; t += 512) Lm[t] = LmuG[t];
  if (tid < NK) ld_s[tid] = ldG[tid];

  stage_tile(WG, &Albuf[0][0], tid);   // state 0 Linv tile
  __syncthreads();

  float vt = 117.62413225f;            // 0.5*D*ln(2*pi); sum_k p_k == 1

  const int sw = (l15 & 7) << 3;       // XOR swizzle term (row&7 == l15&7 since 16|64 are 8-multiples)

  for (int k = 0; k < NK; ++k) {
    if (k < NK - 1) stage_tile(WG + (size_t)(k + 1) * D * D, &Albuf[(k + 1) & 1][0], tid);

    const unsigned short* Ab = &Albuf[k & 1][0];
    f32x4 acc[4][4];
#pragma unroll
    for (int m = 0; m < 4; ++m)
#pragma unroll
      for (int n = 0; n < 4; ++n) acc[m][n] = (f32x4){0.f, 0.f, 0.f, 0.f};

#pragma unroll
    for (int ks = 0; ks < 4; ++ks) {
      const int kbs = (ks * 32 + lg * 8) ^ sw;
      bf16x8 a[4], b[4];
#pragma unroll
      for (int m = 0; m < 4; ++m) {
        const int arow = jg * 64 + m * 16 + l15;
        a[m] = *reinterpret_cast<const bf16x8*>(&Ab[arow * 128 + kbs]);
      }
#pragma unroll
      for (int n = 0; n < 4; ++n) {
        const int brow = bg * 64 + n * 16 + l15;
        b[n] = *reinterpret_cast<const bf16x8*>(&xbuf[brow * 128 + kbs]);
      }
#pragma unroll
      for (int m = 0; m < 4; ++m)
#pragma unroll
        for (int n = 0; n < 4; ++n)
          acc[m][n] = __builtin_amdgcn_mfma_f32_16x16x32_bf16(a[m], b[n], acc[m][n], 0, 0, 0);
    }

    // epilogue: maha partials, lane-local j-reduction then xor-4 across lane groups
    float lmv[4][4];
    const int jb = jg * 64 + lg * 4;
#pragma unroll
    for (int m = 0; m < 4; ++m)
#pragma unroll
      for (int r = 0; r < 4; ++r) lmv[m][r] = Lm[k * D + jb + m * 16 + r];
#pragma unroll
    for (int n = 0; n < 4; ++n) {
      float s = 0.f;
#pragma unroll
      for (int m = 0; m < 4; ++m)
#pragma unroll
        for (int r = 0; r < 4; ++r) {
          const float y = acc[m][n][r] - lmv[m][r];
          s = fmaf(y, y, s);
        }
      s += __shfl_xor(s, 16);
      s += __shfl_xor(s, 32);
      if (ln < 16) mah2[k & 1][jg][bg * 64 + n * 16 + ln] = s;
    }
    __syncthreads();   // also drains vmcnt -> next A tile resident

    if (tid < 256) {
      const float maha = mah2[k & 1][0][tid] + mah2[k & 1][1][tid];
      vt = fmaf(bf2f(pT[tid * 17 + k]), fmaf(0.5f, maha, ld_s[k]), vt);
    }
  }

  if (tid < 256) red[tid] = vt;
  __syncthreads();
  for (int s = 128; s > 0; s >>= 1) {
    if (tid < s) red[tid] += red[tid + s];
    __syncthreads();
  }
  if (tid == 0) atomicAdd(out, red[0] * (1.0f / 64.0f));
}

extern "C" void kernel_launch(void* const* d_in, const int* in_sizes, int n_in,
                              void* d_out, int out_size, void* d_ws, size_t ws_size,
                              hipStream_t stream) {
  const float* x     = (const float*)d_in[0];
  const float* mu    = (const float*)d_in[1];
  const float* sigma = (const float*)d_in[2];
  const float* probs = (const float*)d_in[3];
  float* out = (float*)d_out;

  unsigned short* WG = (unsigned short*)d_ws;          // 16*128*128 bf16 = 512 KB
  float* LmuG = (float*)(WG + (size_t)NK * D * D);     // 8 KB
  float* ldG  = LmuG + NK * D;                         // 64 B

  setup_kernel<<<NK, 128, 0, stream>>>(sigma, mu, WG, LmuG, ldG);
  zero_kernel<<<1, 1, 0, stream>>>(out);
  main_kernel<<<BT / 256, 512, 0, stream>>>(x, probs, WG, LmuG, ldG, out);
}